// Round 1
// baseline (40.172 us; speedup 1.0000x reference)
//
#include <hip/hip_runtime.h>

#define EMB 200
#define U_DIM 32
#define T_DIM 4
#define DIM_A 32
#define NN 10
#define WAVES 4

__global__ __launch_bounds__(WAVES * 64) void gatne_kernel(
    const int* __restrict__ train_inputs,
    const int* __restrict__ train_types,
    const int* __restrict__ node_neigh,
    const float* __restrict__ node_emb,
    const float* __restrict__ node_type_emb,
    const float* __restrict__ tw,
    const float* __restrict__ tw1,
    const float* __restrict__ tw2,
    float* __restrict__ out)
{
    __shared__ float s_nte[WAVES][T_DIM][U_DIM];
    __shared__ float s_comb[WAVES][U_DIM];

    const int wid  = threadIdx.x >> 6;
    const int lane = threadIdx.x & 63;
    const int u    = lane & 31;   // u / a index within half-wave
    const int th   = lane >> 5;   // which half of the wave
    const int b    = blockIdx.x * WAVES + wid;

    const int type = train_types[b];

    // ---- load 40 neighbor indices coalesced into lanes 0..39 ----
    int my_neigh = 0;
    if (lane < T_DIM * NN) my_neigh = node_neigh[b * T_DIM * NN + lane];

    // ---- neighbor sum: half th handles t = {th, 2+th} ----
    #pragma unroll
    for (int tt = 0; tt < 2; ++tt) {
        const int t = tt * 2 + th;
        float acc = 0.f;
        #pragma unroll
        for (int n = 0; n < NN; ++n) {
            const int idx = __shfl(my_neigh, t * NN + n, 64);
            acc += node_type_emb[((long)idx * T_DIM + t) * U_DIM + u];
        }
        s_nte[wid][t][u] = acc;
    }
    __syncthreads();

    // ---- h = tanh(nte @ tw1); scores = h @ tw2 ----
    const float* tw1p = tw1 + type * U_DIM * DIM_A;
    const float  w2   = tw2[type * DIM_A + u];
    float sc[2];
    #pragma unroll
    for (int tt = 0; tt < 2; ++tt) {
        const int t = tt * 2 + th;
        float acc = 0.f;
        #pragma unroll
        for (int uu = 0; uu < U_DIM; ++uu)
            acc += s_nte[wid][t][uu] * tw1p[uu * DIM_A + u];
        float s = tanhf(acc) * w2;
        #pragma unroll
        for (int m = 1; m < 32; m <<= 1) s += __shfl_xor(s, m, 64);
        sc[tt] = s;   // score for t = tt*2 + th, replicated in half
    }
    // exchange halves to get all 4 scores
    const float o0 = __shfl_xor(sc[0], 32, 64);
    const float o1 = __shfl_xor(sc[1], 32, 64);
    const float s0 = th ? o0    : sc[0];
    const float s1 = th ? sc[0] : o0;
    const float s2 = th ? o1    : sc[1];
    const float s3 = th ? sc[1] : o1;

    const float mx = fmaxf(fmaxf(s0, s1), fmaxf(s2, s3));
    const float e0 = expf(s0 - mx), e1 = expf(s1 - mx);
    const float e2 = expf(s2 - mx), e3 = expf(s3 - mx);
    const float inv = 1.f / (e0 + e1 + e2 + e3);

    // ---- comb[u] = sum_t att[t] * nte[t][u] ----
    const float comb = (e0 * s_nte[wid][0][u] + e1 * s_nte[wid][1][u] +
                        e2 * s_nte[wid][2][u] + e3 * s_nte[wid][3][u]) * inv;
    s_comb[wid][u] = comb;
    __syncthreads();

    // ---- node_embed = gathered row + comb @ tw; normalize ----
    const int    node = train_inputs[b];
    const float* twp  = tw + type * U_DIM * EMB;

    float4 v = make_float4(0.f, 0.f, 0.f, 0.f);
    float sumsq = 0.f;
    if (lane < EMB / 4) {   // 50 active lanes, float4 each = 200 floats
        v = *(const float4*)(node_emb + (long)node * EMB + lane * 4);
        #pragma unroll
        for (int uu = 0; uu < U_DIM; ++uu) {
            const float  c = s_comb[wid][uu];
            const float4 w = *(const float4*)(twp + uu * EMB + lane * 4);
            v.x += c * w.x; v.y += c * w.y; v.z += c * w.z; v.w += c * w.w;
        }
        sumsq = v.x * v.x + v.y * v.y + v.z * v.z + v.w * v.w;
    }
    #pragma unroll
    for (int m = 1; m < 64; m <<= 1) sumsq += __shfl_xor(sumsq, m, 64);

    const float rinv = 1.f / fmaxf(sqrtf(sumsq), 1e-12f);
    if (lane < EMB / 4) {
        float4 o = make_float4(v.x * rinv, v.y * rinv, v.z * rinv, v.w * rinv);
        *(float4*)(out + (long)b * EMB + lane * 4) = o;
    }
}

extern "C" void kernel_launch(void* const* d_in, const int* in_sizes, int n_in,
                              void* d_out, int out_size, void* d_ws, size_t ws_size,
                              hipStream_t stream) {
    const int*   train_inputs = (const int*)d_in[0];
    const int*   train_types  = (const int*)d_in[1];
    const int*   node_neigh   = (const int*)d_in[2];
    const float* node_emb     = (const float*)d_in[3];
    const float* node_type_e  = (const float*)d_in[4];
    const float* tw           = (const float*)d_in[5];
    const float* tw1          = (const float*)d_in[6];
    const float* tw2          = (const float*)d_in[7];
    float*       out          = (float*)d_out;

    const int B = in_sizes[0];               // 16384
    const int blocks = B / WAVES;            // 4096

    gatne_kernel<<<blocks, WAVES * 64, 0, stream>>>(
        train_inputs, train_types, node_neigh,
        node_emb, node_type_e, tw, tw1, tw2, out);
}